// Round 3
// baseline (378.245 us; speedup 1.0000x reference)
//
#include <hip/hip_runtime.h>
#include <stdint.h>

#define N_ROWS 32768
#define D_DIM  1024
#define C_TREES 64
#define K_LEAF 16
#define M_OUT  1024

// ---------------- Kernel A: transpose lut (M, C*K=1024) -> lutT (C*K, M) ----------------
__global__ __launch_bounds__(256) void k_transpose(const float* __restrict__ lut,
                                                   float* __restrict__ lutT) {
    __shared__ float tile[32][33];
    int bx = blockIdx.x;          // tile along ck (source col)
    int by = blockIdx.y;          // tile along m  (source row)
    int tx = threadIdx.x;         // 0..31
    int ty = threadIdx.y;         // 0..7
    int src_col = bx * 32 + tx;
#pragma unroll
    for (int i = 0; i < 4; ++i) {
        int src_row = by * 32 + ty + i * 8;
        tile[ty + i * 8][tx] = lut[(size_t)src_row * 1024 + src_col];
    }
    __syncthreads();
    int dst_col = by * 32 + tx;   // m
#pragma unroll
    for (int i = 0; i < 4; ++i) {
        int dst_row = bx * 32 + ty + i * 8;   // ck
        lutT[(size_t)dst_row * 1024 + dst_col] = tile[tx][ty + i * 8];
    }
}

// ---------------- Kernel A2: build pair tables ----------------
// P[p][j][m] = lutT[2p*16 + (j&15)][m] + lutT[(2p+1)*16 + (j>>4)][m]
// Stored with XOR swizzle baked in: float4 chunk g goes to (g&~15)|((g&15)^(j&15)).
__global__ __launch_bounds__(256) void k_build(const float* __restrict__ lutT,
                                               float4* __restrict__ P4) {
    int j = blockIdx.x;           // 0..255 code
    int p = blockIdx.y;           // 0..31 pair
    int klo = j & 15;
    int khi = j >> 4;
    int t = threadIdx.x;          // float4 chunk 0..255
    const float4* a = (const float4*)lutT + (size_t)(p * 32 + klo) * 256;
    const float4* b = (const float4*)lutT + (size_t)(p * 32 + 16 + khi) * 256;
    float4 va = a[t];
    float4 vb = b[t];
    float4 v = make_float4(va.x + vb.x, va.y + vb.y, va.z + vb.z, va.w + vb.w);
    int gsw = (t & ~15) | ((t & 15) ^ klo);
    P4[((size_t)(p * 256 + j)) * 256 + gsw] = v;
}

// ---------------- Kernel B2: encode pair codes ----------------
// code[p][n] = leaf(2p+1)*16 + leaf(2p), u8, p-major.
// Latency-optimized: 4 independent x-gathers + 15-bit compare mask + ALU-only
// bit traversal (no node-dependent LDS gathers in the chain).
__global__ __launch_bounds__(256) void k_encode2(const float* __restrict__ in,
                                                 const int* __restrict__ dims,
                                                 const float* __restrict__ th,
                                                 uint8_t* __restrict__ code) {
    __shared__ float rows[8][1028];   // +4 pad: r-groups land on distinct banks
    __shared__ float th_s[960];
    __shared__ int   dims_s[256];
    int t = threadIdx.x;
    dims_s[t] = dims[t];
    for (int i = t; i < 960; i += 256) th_s[i] = th[i];
    int n0 = blockIdx.x * 8;
    const float4* in4 = (const float4*)(in + (size_t)n0 * 1024);
#pragma unroll
    for (int i = 0; i < 8; ++i) {
        ((float4*)&rows[i][0])[t] = in4[i * 256 + t];
    }
    __syncthreads();
    int p = t >> 3;               // 0..31
    int r = t & 7;                // 0..7
    const float* trow = &rows[r][0];
    int cA = 2 * p, cB = 2 * p + 1;

    float xA[4], xB[4];
#pragma unroll
    for (int l = 0; l < 4; ++l) {
        xA[l] = trow[dims_s[cA * 4 + l]];
        xB[l] = trow[dims_s[cB * 4 + l]];
    }
    const float* tAp = &th_s[cA * 15];
    const float* tBp = &th_s[cB * 15];
    unsigned mA = 0, mB = 0;
#pragma unroll
    for (int i = 0; i < 15; ++i) {
        const int d = (i == 0) ? 0 : (i < 3) ? 1 : (i < 7) ? 2 : 3;  // compile-time
        mA |= ((unsigned)(xA[d] > tAp[i])) << i;
        mB |= ((unsigned)(xB[d] > tBp[i])) << i;
    }
    int nA = 0, nB = 0;
#pragma unroll
    for (int l = 0; l < 4; ++l) {
        nA = 2 * nA + 1 + ((mA >> nA) & 1);
        nB = 2 * nB + 1 + ((mB >> nB) & 1);
    }
    code[(size_t)p * N_ROWS + n0 + r] = (uint8_t)(((nB - 15) << 4) | (nA - 15));
}

// ---------------- Kernel C2: accumulate out[n,m] = sum_p P[p][code][m] ----------------
// Block 512 thr, tile 1024n x 64m. Per p: stage 256x64 f32 slice (64KB) double-buffered
// via global_load_lds(16B), one barrier per p. Swizzle baked into P keeps every aligned
// 8-lane b128 phase within one 128B region (conflict-free).
// Default dispatch: bid = bx + 16*by, 16==0 mod 8 -> XCD = bx%8 -> each XCD's L2 holds
// exactly its 2 m-slices of P (4MB) -- already XCD-optimal.
__global__ __launch_bounds__(512, 2) void k_accum2(const float4* __restrict__ P4,
                                                   const uint8_t* __restrict__ code,
                                                   float* __restrict__ out) {
    __shared__ float4 sl[2][4096];    // 2 x 64KB

    int t  = threadIdx.x;
    int mc = t & 15;                  // float4 chunk within m-tile (16 chunks = 64 m)
    int ng = t >> 4;                  // 0..31, each owns 32 n rows
    int m0 = blockIdx.x * 64;
    int n0 = blockIdx.y * 1024;

    auto stage = [&](int buf, int p) {
#pragma unroll
        for (int it = 0; it < 8; ++it) {
            int idx = t + it * 512;                    // 0..4095 float4 within slice
            int row = idx >> 4;
            int ch  = idx & 15;
            const float4* src = P4 + ((size_t)(p * 256 + row)) * 256 + (m0 >> 2) + ch;
            __builtin_amdgcn_global_load_lds((const __attribute__((address_space(1))) void*)src,
                                             (__attribute__((address_space(3))) void*)(&sl[buf][idx]),
                                             16, 0, 0);
        }
    };

    float4 acc[32];
#pragma unroll
    for (int j = 0; j < 32; ++j) acc[j] = make_float4(0.f, 0.f, 0.f, 0.f);

    const uint8_t* cp = code + n0 + ng * 32;
    uint64_t cd[4];
#pragma unroll
    for (int q = 0; q < 4; ++q) cd[q] = ((const uint64_t*)cp)[q];   // codes for p=0
    stage(0, 0);

    for (int p = 0; p < 32; ++p) {
        __syncthreads();                       // stage(p) drained
        if (p < 31) stage((p + 1) & 1, p + 1); // next slice in flight across compute
        uint64_t nx0 = 0, nx1 = 0, nx2 = 0, nx3 = 0;
        if (p < 31) {
            const uint64_t* np = (const uint64_t*)(cp + (size_t)(p + 1) * N_ROWS);
            nx0 = np[0]; nx1 = np[1]; nx2 = np[2]; nx3 = np[3];
        }
        int buf = p & 1;
        const float4* s = &sl[buf][0];
#pragma unroll
        for (int j = 0; j < 32; ++j) {
            int cv = (int)((cd[j >> 3] >> ((j & 7) * 8)) & 0xff);
            int idx = (cv << 4) | (mc ^ (cv & 15));
            float4 v = s[idx];
            acc[j].x += v.x; acc[j].y += v.y; acc[j].z += v.z; acc[j].w += v.w;
        }
        cd[0] = nx0; cd[1] = nx1; cd[2] = nx2; cd[3] = nx3;
    }

    float4* out4 = (float4*)out;
#pragma unroll
    for (int j = 0; j < 32; ++j) {
        int n = n0 + ng * 32 + j;
        out4[(size_t)n * 256 + (m0 >> 2) + mc] = acc[j];
    }
}

// ================= Fallback path (ws too small): round-1 kernels =================
__global__ __launch_bounds__(256) void k_encode(const float* __restrict__ in,
                                                const int* __restrict__ dims,
                                                const float* __restrict__ th,
                                                uint8_t* __restrict__ leaf) {
    __shared__ float rows[8][1028];
    __shared__ float th_s[960];
    __shared__ int   dims_s[256];
    int t = threadIdx.x;
    dims_s[t] = dims[t];
    for (int i = t; i < 960; i += 256) th_s[i] = th[i];
    int n0 = blockIdx.x * 8;
    const float4* in4 = (const float4*)(in + (size_t)n0 * 1024);
#pragma unroll
    for (int i = 0; i < 8; ++i) {
        ((float4*)&rows[i][0])[t] = in4[i * 256 + t];
    }
    __syncthreads();
#pragma unroll
    for (int i = 0; i < 2; ++i) {
        int id = i * 256 + t;
        int c = id >> 3;
        int r = id & 7;
        int node = 0;
        const float* trow = &rows[r][0];
#pragma unroll
        for (int lvl = 0; lvl < 4; ++lvl) {
            float x   = trow[dims_s[c * 4 + lvl]];
            float thv = th_s[c * 15 + node];
            node = 2 * node + 1 + ((x > thv) ? 1 : 0);
        }
        leaf[(size_t)c * N_ROWS + n0 + r] = (uint8_t)(node - 15);
    }
}

__global__ __launch_bounds__(512) void k_accum(const float* __restrict__ lutT,
                                               const uint8_t* __restrict__ leaf,
                                               float* __restrict__ out) {
    __shared__ float4 sl[2][16][32];
    int t     = threadIdx.x;
    int mlane = t & 31;
    int ngrp  = t >> 5;
    int wave  = t >> 6;
    int lane  = t & 63;
    int srow  = 2 * wave + (lane >> 5);
    int schunk = lane & 31;
    int m0 = blockIdx.x * 128;
    int n0 = blockIdx.y * 128;
    const float4* lutT4 = (const float4*)lutT;
    auto stage = [&](int buf, int c) {
        const float4* src = lutT4 + ((size_t)(c * 16 + srow) * 256) + (m0 >> 2) + schunk;
        __builtin_amdgcn_global_load_lds((const __attribute__((address_space(1))) void*)src,
                                         (__attribute__((address_space(3))) void*)&sl[buf][2 * wave][0],
                                         16, 0, 0);
    };
    float4 acc[8];
#pragma unroll
    for (int j = 0; j < 8; ++j) acc[j] = make_float4(0.f, 0.f, 0.f, 0.f);
    const uint8_t* lp = leaf + n0 + ngrp * 8;
    uint64_t lv = *(const uint64_t*)lp;
    stage(0, 0);
#pragma unroll 2
    for (int c = 0; c < 64; ++c) {
        __syncthreads();
        if (c < 63) stage((c + 1) & 1, c + 1);
        uint64_t lv_next = (c < 63) ? *(const uint64_t*)(lp + (size_t)(c + 1) * N_ROWS) : 0ull;
        int buf = c & 1;
#pragma unroll
        for (int j = 0; j < 8; ++j) {
            int k = (int)((lv >> (8 * j)) & 15);
            float4 v = sl[buf][k][mlane];
            acc[j].x += v.x; acc[j].y += v.y; acc[j].z += v.z; acc[j].w += v.w;
        }
        lv = lv_next;
    }
    float4* out4 = (float4*)out;
#pragma unroll
    for (int j = 0; j < 8; ++j) {
        int n = n0 + ngrp * 8 + j;
        out4[(size_t)n * 256 + (m0 >> 2) + mlane] = acc[j];
    }
}

extern "C" void kernel_launch(void* const* d_in, const int* in_sizes, int n_in,
                              void* d_out, int out_size, void* d_ws, size_t ws_size,
                              hipStream_t stream) {
    const float* inputMatrix = (const float*)d_in[0];
    const int*   dims        = (const int*)d_in[1];
    const float* thresholds  = (const float*)d_in[2];
    const float* lut         = (const float*)d_in[3];
    float* out = (float*)d_out;

    float* lutT = (float*)d_ws;                                    // 4 MB

    const size_t NEED = (size_t)4 * 1024 * 1024   // lutT
                      + (size_t)32 * 1024 * 1024  // P
                      + (size_t)1 * 1024 * 1024;  // code

    if (ws_size >= NEED) {
        float4*  P4   = (float4*)((char*)d_ws + (size_t)4 * 1024 * 1024);   // 32 MB
        uint8_t* codep = (uint8_t*)d_ws + (size_t)36 * 1024 * 1024;         // 1 MB

        k_transpose<<<dim3(32, 32), dim3(32, 8), 0, stream>>>(lut, lutT);
        k_build<<<dim3(256, 32), 256, 0, stream>>>(lutT, P4);
        k_encode2<<<N_ROWS / 8, 256, 0, stream>>>(inputMatrix, dims, thresholds, codep);
        k_accum2<<<dim3(M_OUT / 64, N_ROWS / 1024), 512, 0, stream>>>(P4, codep, out);
    } else {
        uint8_t* leaf = (uint8_t*)d_ws + (size_t)4 * 1024 * 1024;
        k_transpose<<<dim3(32, 32), dim3(32, 8), 0, stream>>>(lut, lutT);
        k_encode<<<N_ROWS / 8, 256, 0, stream>>>(inputMatrix, dims, thresholds, leaf);
        k_accum<<<dim3(M_OUT / 128, N_ROWS / 128), 512, 0, stream>>>(lutT, leaf, out);
    }
}

// Round 4
// 337.685 us; speedup vs baseline: 1.1201x; 1.1201x over previous
//
#include <hip/hip_runtime.h>
#include <stdint.h>

#define N_ROWS 32768
#define D_DIM  1024
#define C_TREES 64
#define K_LEAF 16
#define M_OUT  1024

// ---------------- Kernel A: transpose lut (M, C*K=1024) -> lutT (C*K, M) ----------------
__global__ __launch_bounds__(256) void k_transpose(const float* __restrict__ lut,
                                                   float* __restrict__ lutT) {
    __shared__ float tile[32][33];
    int bx = blockIdx.x;          // tile along ck (source col)
    int by = blockIdx.y;          // tile along m  (source row)
    int tx = threadIdx.x;         // 0..31
    int ty = threadIdx.y;         // 0..7
    int src_col = bx * 32 + tx;
#pragma unroll
    for (int i = 0; i < 4; ++i) {
        int src_row = by * 32 + ty + i * 8;
        tile[ty + i * 8][tx] = lut[(size_t)src_row * 1024 + src_col];
    }
    __syncthreads();
    int dst_col = by * 32 + tx;   // m
#pragma unroll
    for (int i = 0; i < 4; ++i) {
        int dst_row = bx * 32 + ty + i * 8;   // ck
        lutT[(size_t)dst_row * 1024 + dst_col] = tile[tx][ty + i * 8];
    }
}

// ---------------- Kernel A2: build pair tables ----------------
// P[p][j][m] = lutT[2p*16 + (j&15)][m] + lutT[(2p+1)*16 + (j>>4)][m]
// Swizzle baked in within each aligned 8-float4 group:
//   float4 chunk g -> (g&~7)|((g&7)^(klo&7)).
__global__ __launch_bounds__(256) void k_build(const float* __restrict__ lutT,
                                               float4* __restrict__ P4) {
    int j = blockIdx.x;           // 0..255 code
    int p = blockIdx.y;           // 0..31 pair
    int klo = j & 15;
    int khi = j >> 4;
    int t = threadIdx.x;          // float4 chunk 0..255
    const float4* a = (const float4*)lutT + (size_t)(p * 32 + klo) * 256;
    const float4* b = (const float4*)lutT + (size_t)(p * 32 + 16 + khi) * 256;
    float4 va = a[t];
    float4 vb = b[t];
    float4 v = make_float4(va.x + vb.x, va.y + vb.y, va.z + vb.z, va.w + vb.w);
    int gsw = (t & ~7) | ((t & 7) ^ (klo & 7));
    P4[((size_t)(p * 256 + j)) * 256 + gsw] = v;
}

// ---------------- Kernel B2: encode pair codes ----------------
// code[p][n] = leaf(2p+1)*16 + leaf(2p), u8, p-major.
// Latency-optimized: 4 independent x-gathers + 15-bit compare mask + ALU-only
// bit traversal (no node-dependent LDS gathers in the chain).
__global__ __launch_bounds__(256) void k_encode2(const float* __restrict__ in,
                                                 const int* __restrict__ dims,
                                                 const float* __restrict__ th,
                                                 uint8_t* __restrict__ code) {
    __shared__ float rows[8][1028];   // +4 pad: r-groups land on distinct banks
    __shared__ float th_s[960];
    __shared__ int   dims_s[256];
    int t = threadIdx.x;
    dims_s[t] = dims[t];
    for (int i = t; i < 960; i += 256) th_s[i] = th[i];
    int n0 = blockIdx.x * 8;
    const float4* in4 = (const float4*)(in + (size_t)n0 * 1024);
#pragma unroll
    for (int i = 0; i < 8; ++i) {
        ((float4*)&rows[i][0])[t] = in4[i * 256 + t];
    }
    __syncthreads();
    int p = t >> 3;               // 0..31
    int r = t & 7;                // 0..7
    const float* trow = &rows[r][0];
    int cA = 2 * p, cB = 2 * p + 1;

    float xA[4], xB[4];
#pragma unroll
    for (int l = 0; l < 4; ++l) {
        xA[l] = trow[dims_s[cA * 4 + l]];
        xB[l] = trow[dims_s[cB * 4 + l]];
    }
    const float* tAp = &th_s[cA * 15];
    const float* tBp = &th_s[cB * 15];
    unsigned mA = 0, mB = 0;
#pragma unroll
    for (int i = 0; i < 15; ++i) {
        const int d = (i == 0) ? 0 : (i < 3) ? 1 : (i < 7) ? 2 : 3;  // compile-time
        mA |= ((unsigned)(xA[d] > tAp[i])) << i;
        mB |= ((unsigned)(xB[d] > tBp[i])) << i;
    }
    int nA = 0, nB = 0;
#pragma unroll
    for (int l = 0; l < 4; ++l) {
        nA = 2 * nA + 1 + ((mA >> nA) & 1);
        nB = 2 * nB + 1 + ((mB >> nB) & 1);
    }
    code[(size_t)p * N_ROWS + n0 + r] = (uint8_t)(((nB - 15) << 4) | (nA - 15));
}

// ---------------- Kernel C3: accumulate out[n,m] = sum_p P[p][code][m] ----------------
// Block 512 thr, tile 1024n x 32m. Per p: stage 256x32 f32 slice (32KB),
// double-buffered (64KB total -> 2 blocks/CU, 16 waves/CU), one barrier per p.
// Per-wave read: 8 groups x 8 chunks, rows bank-aligned, XOR swizzle bijective
// within 8-chunk groups -> each bank hit exactly 8x = the 1024B/128B floor.
__global__ __launch_bounds__(512, 4) void k_accum3(const float4* __restrict__ P4,
                                                   const uint8_t* __restrict__ code,
                                                   float* __restrict__ out) {
    __shared__ float4 sl[2][2048];    // 2 x 32KB

    int t  = threadIdx.x;
    int mc = t & 7;                   // float4 chunk within m-tile (8 chunks = 32 m)
    int ng = t >> 3;                  // 0..63, each owns 16 n rows
    int m0 = blockIdx.x * 32;
    int n0 = blockIdx.y * 1024;

    auto stage = [&](int buf, int p) {
#pragma unroll
        for (int it = 0; it < 4; ++it) {
            int idx = t + it * 512;                    // 0..2047 float4 within slice
            int row = idx >> 3;
            int ch  = idx & 7;
            const float4* src = P4 + ((size_t)(p * 256 + row)) * 256 + (m0 >> 2) + ch;
            __builtin_amdgcn_global_load_lds((const __attribute__((address_space(1))) void*)src,
                                             (__attribute__((address_space(3))) void*)(&sl[buf][idx]),
                                             16, 0, 0);
        }
    };

    float4 acc[16];
#pragma unroll
    for (int j = 0; j < 16; ++j) acc[j] = make_float4(0.f, 0.f, 0.f, 0.f);

    const uint8_t* cp = code + n0 + ng * 16;
    uint64_t cd0 = ((const uint64_t*)cp)[0];
    uint64_t cd1 = ((const uint64_t*)cp)[1];
    stage(0, 0);

    for (int p = 0; p < 32; ++p) {
        __syncthreads();                       // stage(p) drained (vmcnt0 before barrier)
        if (p < 31) stage((p + 1) & 1, p + 1); // next slice in flight across compute
        uint64_t nx0 = 0, nx1 = 0;
        if (p < 31) {
            const uint64_t* np = (const uint64_t*)(cp + (size_t)(p + 1) * N_ROWS);
            nx0 = np[0]; nx1 = np[1];
        }
        int buf = p & 1;
        const float4* s = &sl[buf][0];
#pragma unroll
        for (int j = 0; j < 16; ++j) {
            int cv = (int)(((j < 8 ? cd0 : cd1) >> ((j & 7) * 8)) & 0xff);
            int idx = (cv << 3) | (mc ^ (cv & 7));
            float4 v = s[idx];
            acc[j].x += v.x; acc[j].y += v.y; acc[j].z += v.z; acc[j].w += v.w;
        }
        cd0 = nx0; cd1 = nx1;
    }

    float4* out4 = (float4*)out;
#pragma unroll
    for (int j = 0; j < 16; ++j) {
        int n = n0 + ng * 16 + j;
        out4[(size_t)n * 256 + (m0 >> 2) + mc] = acc[j];
    }
}

// ================= Fallback path (ws too small): round-1 kernels =================
__global__ __launch_bounds__(256) void k_encode(const float* __restrict__ in,
                                                const int* __restrict__ dims,
                                                const float* __restrict__ th,
                                                uint8_t* __restrict__ leaf) {
    __shared__ float rows[8][1028];
    __shared__ float th_s[960];
    __shared__ int   dims_s[256];
    int t = threadIdx.x;
    dims_s[t] = dims[t];
    for (int i = t; i < 960; i += 256) th_s[i] = th[i];
    int n0 = blockIdx.x * 8;
    const float4* in4 = (const float4*)(in + (size_t)n0 * 1024);
#pragma unroll
    for (int i = 0; i < 8; ++i) {
        ((float4*)&rows[i][0])[t] = in4[i * 256 + t];
    }
    __syncthreads();
#pragma unroll
    for (int i = 0; i < 2; ++i) {
        int id = i * 256 + t;
        int c = id >> 3;
        int r = id & 7;
        int node = 0;
        const float* trow = &rows[r][0];
#pragma unroll
        for (int lvl = 0; lvl < 4; ++lvl) {
            float x   = trow[dims_s[c * 4 + lvl]];
            float thv = th_s[c * 15 + node];
            node = 2 * node + 1 + ((x > thv) ? 1 : 0);
        }
        leaf[(size_t)c * N_ROWS + n0 + r] = (uint8_t)(node - 15);
    }
}

__global__ __launch_bounds__(512) void k_accum(const float* __restrict__ lutT,
                                               const uint8_t* __restrict__ leaf,
                                               float* __restrict__ out) {
    __shared__ float4 sl[2][16][32];
    int t     = threadIdx.x;
    int mlane = t & 31;
    int ngrp  = t >> 5;
    int wave  = t >> 6;
    int lane  = t & 63;
    int srow  = 2 * wave + (lane >> 5);
    int schunk = lane & 31;
    int m0 = blockIdx.x * 128;
    int n0 = blockIdx.y * 128;
    const float4* lutT4 = (const float4*)lutT;
    auto stage = [&](int buf, int c) {
        const float4* src = lutT4 + ((size_t)(c * 16 + srow) * 256) + (m0 >> 2) + schunk;
        __builtin_amdgcn_global_load_lds((const __attribute__((address_space(1))) void*)src,
                                         (__attribute__((address_space(3))) void*)&sl[buf][2 * wave][0],
                                         16, 0, 0);
    };
    float4 acc[8];
#pragma unroll
    for (int j = 0; j < 8; ++j) acc[j] = make_float4(0.f, 0.f, 0.f, 0.f);
    const uint8_t* lp = leaf + n0 + ngrp * 8;
    uint64_t lv = *(const uint64_t*)lp;
    stage(0, 0);
#pragma unroll 2
    for (int c = 0; c < 64; ++c) {
        __syncthreads();
        if (c < 63) stage((c + 1) & 1, c + 1);
        uint64_t lv_next = (c < 63) ? *(const uint64_t*)(lp + (size_t)(c + 1) * N_ROWS) : 0ull;
        int buf = c & 1;
#pragma unroll
        for (int j = 0; j < 8; ++j) {
            int k = (int)((lv >> (8 * j)) & 15);
            float4 v = sl[buf][k][mlane];
            acc[j].x += v.x; acc[j].y += v.y; acc[j].z += v.z; acc[j].w += v.w;
        }
        lv = lv_next;
    }
    float4* out4 = (float4*)out;
#pragma unroll
    for (int j = 0; j < 8; ++j) {
        int n = n0 + ngrp * 8 + j;
        out4[(size_t)n * 256 + (m0 >> 2) + mlane] = acc[j];
    }
}

extern "C" void kernel_launch(void* const* d_in, const int* in_sizes, int n_in,
                              void* d_out, int out_size, void* d_ws, size_t ws_size,
                              hipStream_t stream) {
    const float* inputMatrix = (const float*)d_in[0];
    const int*   dims        = (const int*)d_in[1];
    const float* thresholds  = (const float*)d_in[2];
    const float* lut         = (const float*)d_in[3];
    float* out = (float*)d_out;

    float* lutT = (float*)d_ws;                                    // 4 MB

    const size_t NEED = (size_t)4 * 1024 * 1024   // lutT
                      + (size_t)32 * 1024 * 1024  // P
                      + (size_t)1 * 1024 * 1024;  // code

    if (ws_size >= NEED) {
        float4*  P4    = (float4*)((char*)d_ws + (size_t)4 * 1024 * 1024);  // 32 MB
        uint8_t* codep = (uint8_t*)d_ws + (size_t)36 * 1024 * 1024;         // 1 MB

        k_transpose<<<dim3(32, 32), dim3(32, 8), 0, stream>>>(lut, lutT);
        k_build<<<dim3(256, 32), 256, 0, stream>>>(lutT, P4);
        k_encode2<<<N_ROWS / 8, 256, 0, stream>>>(inputMatrix, dims, thresholds, codep);
        k_accum3<<<dim3(M_OUT / 32, N_ROWS / 1024), 512, 0, stream>>>(P4, codep, out);
    } else {
        uint8_t* leaf = (uint8_t*)d_ws + (size_t)4 * 1024 * 1024;
        k_transpose<<<dim3(32, 32), dim3(32, 8), 0, stream>>>(lut, lutT);
        k_encode<<<N_ROWS / 8, 256, 0, stream>>>(inputMatrix, dims, thresholds, leaf);
        k_accum<<<dim3(M_OUT / 128, N_ROWS / 128), 512, 0, stream>>>(lutT, leaf, out);
    }
}

// Round 5
// 332.285 us; speedup vs baseline: 1.1383x; 1.0162x over previous
//
#include <hip/hip_runtime.h>
#include <stdint.h>

#define N_ROWS 32768
#define D_DIM  1024
#define C_TREES 64
#define K_LEAF 16
#define M_OUT  1024

typedef _Float16 half8v __attribute__((ext_vector_type(8)));
typedef _Float16 half4v __attribute__((ext_vector_type(4)));

// ---------------- Kernel A: transpose lut (M, C*K=1024) -> lutT (C*K, M) ----------------
__global__ __launch_bounds__(256) void k_transpose(const float* __restrict__ lut,
                                                   float* __restrict__ lutT) {
    __shared__ float tile[32][33];
    int bx = blockIdx.x;          // tile along ck (source col)
    int by = blockIdx.y;          // tile along m  (source row)
    int tx = threadIdx.x;         // 0..31
    int ty = threadIdx.y;         // 0..7
    int src_col = bx * 32 + tx;
#pragma unroll
    for (int i = 0; i < 4; ++i) {
        int src_row = by * 32 + ty + i * 8;
        tile[ty + i * 8][tx] = lut[(size_t)src_row * 1024 + src_col];
    }
    __syncthreads();
    int dst_col = by * 32 + tx;   // m
#pragma unroll
    for (int i = 0; i < 4; ++i) {
        int dst_row = bx * 32 + ty + i * 8;   // ck
        lutT[(size_t)dst_row * 1024 + dst_col] = tile[tx][ty + i * 8];
    }
}

// ---------------- Kernel A2h: build pair tables in f16 ----------------
// Ph[p][j][m] = (f16)( lutT[2p*16 + (j&15)][m] + lutT[(2p+1)*16 + (j>>4)][m] )
// Linear layout, no swizzle (intra-row swizzle proved useless for cross-group conflicts).
__global__ __launch_bounds__(256) void k_build_h(const float* __restrict__ lutT,
                                                 _Float16* __restrict__ Ph) {
    int j = blockIdx.x;           // 0..255 code
    int p = blockIdx.y;           // 0..31 pair
    int klo = j & 15;
    int khi = j >> 4;
    int t = threadIdx.x;          // 0..255, 4 m each
    const float4* a = (const float4*)lutT + (size_t)(p * 32 + klo) * 256;
    const float4* b = (const float4*)lutT + (size_t)(p * 32 + 16 + khi) * 256;
    float4 va = a[t];
    float4 vb = b[t];
    half4v hv;
    hv.x = (_Float16)(va.x + vb.x);
    hv.y = (_Float16)(va.y + vb.y);
    hv.z = (_Float16)(va.z + vb.z);
    hv.w = (_Float16)(va.w + vb.w);
    ((half4v*)Ph)[(size_t)(p * 256 + j) * 256 + t] = hv;   // 8B store
}

// ---------------- Kernel B2: encode pair codes ----------------
// code[p][n] = leaf(2p+1)*16 + leaf(2p), u8, p-major.
__global__ __launch_bounds__(256) void k_encode2(const float* __restrict__ in,
                                                 const int* __restrict__ dims,
                                                 const float* __restrict__ th,
                                                 uint8_t* __restrict__ code) {
    __shared__ float rows[8][1028];   // +4 pad
    __shared__ float th_s[960];
    __shared__ int   dims_s[256];
    int t = threadIdx.x;
    dims_s[t] = dims[t];
    for (int i = t; i < 960; i += 256) th_s[i] = th[i];
    int n0 = blockIdx.x * 8;
    const float4* in4 = (const float4*)(in + (size_t)n0 * 1024);
#pragma unroll
    for (int i = 0; i < 8; ++i) {
        ((float4*)&rows[i][0])[t] = in4[i * 256 + t];
    }
    __syncthreads();
    int p = t >> 3;               // 0..31
    int r = t & 7;                // 0..7
    const float* trow = &rows[r][0];
    int cA = 2 * p, cB = 2 * p + 1;

    float xA[4], xB[4];
#pragma unroll
    for (int l = 0; l < 4; ++l) {
        xA[l] = trow[dims_s[cA * 4 + l]];
        xB[l] = trow[dims_s[cB * 4 + l]];
    }
    const float* tAp = &th_s[cA * 15];
    const float* tBp = &th_s[cB * 15];
    unsigned mA = 0, mB = 0;
#pragma unroll
    for (int i = 0; i < 15; ++i) {
        const int d = (i == 0) ? 0 : (i < 3) ? 1 : (i < 7) ? 2 : 3;  // compile-time
        mA |= ((unsigned)(xA[d] > tAp[i])) << i;
        mB |= ((unsigned)(xB[d] > tBp[i])) << i;
    }
    int nA = 0, nB = 0;
#pragma unroll
    for (int l = 0; l < 4; ++l) {
        nA = 2 * nA + 1 + ((mA >> nA) & 1);
        nB = 2 * nB + 1 + ((mB >> nB) & 1);
    }
    code[(size_t)p * N_ROWS + n0 + r] = (uint8_t)(((nB - 15) << 4) | (nA - 15));
}

// ---------------- Kernel C4: f16 accumulate out[n,m] = sum_p Ph[p][code][m] ----------------
// Block 512 thr, tile 512n x 64m. Per p: stage 256 rows x 128B f16 slice (32KB),
// double-buffered (64KB -> 2 blocks/CU, 16 waves/CU). Lane reads b128 = 8 f16 = 8 m.
// LDS read volume halves vs f32: 2.15 GB -> ~41us floor + conflict tax.
__global__ __launch_bounds__(512, 4) void k_accum4(const float4* __restrict__ P4h,
                                                   const uint8_t* __restrict__ code,
                                                   float* __restrict__ out) {
    __shared__ float4 sl[2][2048];    // 2 x 32KB : 256 rows x 8 float4 (64 f16 = 64 m)

    int t  = threadIdx.x;
    int mc = t & 7;                   // 16B chunk within row (8 chunks = 64 m)
    int ng = t >> 3;                  // 0..63, each owns 8 n rows
    int m0 = blockIdx.x * 64;
    int n0 = blockIdx.y * 512;

    auto stage = [&](int buf, int p) {
#pragma unroll
        for (int it = 0; it < 4; ++it) {
            int idx = t + it * 512;                    // 0..2047 float4 within slice
            int row = idx >> 3;
            int ch  = idx & 7;
            const float4* src = P4h + ((size_t)(p * 256 + row)) * 128 + (m0 >> 3) + ch;
            __builtin_amdgcn_global_load_lds((const __attribute__((address_space(1))) void*)src,
                                             (__attribute__((address_space(3))) void*)(&sl[buf][idx]),
                                             16, 0, 0);
        }
    };

    float acc[8][8];
#pragma unroll
    for (int j = 0; j < 8; ++j)
#pragma unroll
        for (int q = 0; q < 8; ++q) acc[j][q] = 0.f;

    const uint8_t* cp = code + n0 + ng * 8;
    uint64_t cd = *(const uint64_t*)cp;          // codes for p=0
    stage(0, 0);

    for (int p = 0; p < 32; ++p) {
        __syncthreads();                       // stage(p) drained (vmcnt0 before barrier)
        if (p < 31) stage((p + 1) & 1, p + 1); // next slice in flight across compute
        uint64_t nx = 0;
        if (p < 31) nx = *(const uint64_t*)(cp + (size_t)(p + 1) * N_ROWS);
        const float4* s = &sl[p & 1][0];
#pragma unroll
        for (int j = 0; j < 8; ++j) {
            int cv = (int)((cd >> (8 * j)) & 0xff);
            float4 v = s[cv * 8 + mc];
            half8v h = __builtin_bit_cast(half8v, v);
#pragma unroll
            for (int q = 0; q < 8; ++q) acc[j][q] += (float)h[q];
        }
        cd = nx;
    }

    float4* out4 = (float4*)out;
#pragma unroll
    for (int j = 0; j < 8; ++j) {
        int n = n0 + ng * 8 + j;
        size_t base = (size_t)n * 256 + (m0 >> 2) + mc * 2;
        out4[base]     = make_float4(acc[j][0], acc[j][1], acc[j][2], acc[j][3]);
        out4[base + 1] = make_float4(acc[j][4], acc[j][5], acc[j][6], acc[j][7]);
    }
}

// ================= Fallback path (ws too small): round-1 kernels =================
__global__ __launch_bounds__(256) void k_encode(const float* __restrict__ in,
                                                const int* __restrict__ dims,
                                                const float* __restrict__ th,
                                                uint8_t* __restrict__ leaf) {
    __shared__ float rows[8][1028];
    __shared__ float th_s[960];
    __shared__ int   dims_s[256];
    int t = threadIdx.x;
    dims_s[t] = dims[t];
    for (int i = t; i < 960; i += 256) th_s[i] = th[i];
    int n0 = blockIdx.x * 8;
    const float4* in4 = (const float4*)(in + (size_t)n0 * 1024);
#pragma unroll
    for (int i = 0; i < 8; ++i) {
        ((float4*)&rows[i][0])[t] = in4[i * 256 + t];
    }
    __syncthreads();
#pragma unroll
    for (int i = 0; i < 2; ++i) {
        int id = i * 256 + t;
        int c = id >> 3;
        int r = id & 7;
        int node = 0;
        const float* trow = &rows[r][0];
#pragma unroll
        for (int lvl = 0; lvl < 4; ++lvl) {
            float x   = trow[dims_s[c * 4 + lvl]];
            float thv = th_s[c * 15 + node];
            node = 2 * node + 1 + ((x > thv) ? 1 : 0);
        }
        leaf[(size_t)c * N_ROWS + n0 + r] = (uint8_t)(node - 15);
    }
}

__global__ __launch_bounds__(512) void k_accum(const float* __restrict__ lutT,
                                               const uint8_t* __restrict__ leaf,
                                               float* __restrict__ out) {
    __shared__ float4 sl[2][16][32];
    int t     = threadIdx.x;
    int mlane = t & 31;
    int ngrp  = t >> 5;
    int wave  = t >> 6;
    int lane  = t & 63;
    int srow  = 2 * wave + (lane >> 5);
    int schunk = lane & 31;
    int m0 = blockIdx.x * 128;
    int n0 = blockIdx.y * 128;
    const float4* lutT4 = (const float4*)lutT;
    auto stage = [&](int buf, int c) {
        const float4* src = lutT4 + ((size_t)(c * 16 + srow) * 256) + (m0 >> 2) + schunk;
        __builtin_amdgcn_global_load_lds((const __attribute__((address_space(1))) void*)src,
                                         (__attribute__((address_space(3))) void*)&sl[buf][2 * wave][0],
                                         16, 0, 0);
    };
    float4 acc[8];
#pragma unroll
    for (int j = 0; j < 8; ++j) acc[j] = make_float4(0.f, 0.f, 0.f, 0.f);
    const uint8_t* lp = leaf + n0 + ngrp * 8;
    uint64_t lv = *(const uint64_t*)lp;
    stage(0, 0);
#pragma unroll 2
    for (int c = 0; c < 64; ++c) {
        __syncthreads();
        if (c < 63) stage((c + 1) & 1, c + 1);
        uint64_t lv_next = (c < 63) ? *(const uint64_t*)(lp + (size_t)(c + 1) * N_ROWS) : 0ull;
        int buf = c & 1;
#pragma unroll
        for (int j = 0; j < 8; ++j) {
            int k = (int)((lv >> (8 * j)) & 15);
            float4 v = sl[buf][k][mlane];
            acc[j].x += v.x; acc[j].y += v.y; acc[j].z += v.z; acc[j].w += v.w;
        }
        lv = lv_next;
    }
    float4* out4 = (float4*)out;
#pragma unroll
    for (int j = 0; j < 8; ++j) {
        int n = n0 + ngrp * 8 + j;
        out4[(size_t)n * 256 + (m0 >> 2) + mlane] = acc[j];
    }
}

extern "C" void kernel_launch(void* const* d_in, const int* in_sizes, int n_in,
                              void* d_out, int out_size, void* d_ws, size_t ws_size,
                              hipStream_t stream) {
    const float* inputMatrix = (const float*)d_in[0];
    const int*   dims        = (const int*)d_in[1];
    const float* thresholds  = (const float*)d_in[2];
    const float* lut         = (const float*)d_in[3];
    float* out = (float*)d_out;

    float* lutT = (float*)d_ws;                                    // 4 MB

    const size_t NEED = (size_t)4 * 1024 * 1024   // lutT
                      + (size_t)16 * 1024 * 1024  // Ph (f16)
                      + (size_t)1 * 1024 * 1024;  // code

    if (ws_size >= NEED) {
        _Float16* Ph   = (_Float16*)((char*)d_ws + (size_t)4 * 1024 * 1024); // 16 MB
        uint8_t* codep = (uint8_t*)d_ws + (size_t)20 * 1024 * 1024;          // 1 MB

        k_transpose<<<dim3(32, 32), dim3(32, 8), 0, stream>>>(lut, lutT);
        k_build_h<<<dim3(256, 32), 256, 0, stream>>>(lutT, Ph);
        k_encode2<<<N_ROWS / 8, 256, 0, stream>>>(inputMatrix, dims, thresholds, codep);
        k_accum4<<<dim3(M_OUT / 64, N_ROWS / 512), 512, 0, stream>>>((const float4*)Ph, codep, out);
    } else {
        uint8_t* leaf = (uint8_t*)d_ws + (size_t)4 * 1024 * 1024;
        k_transpose<<<dim3(32, 32), dim3(32, 8), 0, stream>>>(lut, lutT);
        k_encode<<<N_ROWS / 8, 256, 0, stream>>>(inputMatrix, dims, thresholds, leaf);
        k_accum<<<dim3(M_OUT / 128, N_ROWS / 128), 512, 0, stream>>>(lutT, leaf, out);
    }
}

// Round 6
// 318.540 us; speedup vs baseline: 1.1874x; 1.0432x over previous
//
#include <hip/hip_runtime.h>
#include <stdint.h>

#define N_ROWS 32768
#define D_DIM  1024
#define C_TREES 64
#define K_LEAF 16
#define M_OUT  1024

typedef _Float16 half8v __attribute__((ext_vector_type(8)));
typedef _Float16 half4v __attribute__((ext_vector_type(4)));

// ---------------- Kernel A: transpose lut (M, C*K=1024) -> lutT (C*K, M) ----------------
__global__ __launch_bounds__(256) void k_transpose(const float* __restrict__ lut,
                                                   float* __restrict__ lutT) {
    __shared__ float tile[32][33];
    int bx = blockIdx.x;          // tile along ck (source col)
    int by = blockIdx.y;          // tile along m  (source row)
    int tx = threadIdx.x;         // 0..31
    int ty = threadIdx.y;         // 0..7
    int src_col = bx * 32 + tx;
#pragma unroll
    for (int i = 0; i < 4; ++i) {
        int src_row = by * 32 + ty + i * 8;
        tile[ty + i * 8][tx] = lut[(size_t)src_row * 1024 + src_col];
    }
    __syncthreads();
    int dst_col = by * 32 + tx;   // m
#pragma unroll
    for (int i = 0; i < 4; ++i) {
        int dst_row = bx * 32 + ty + i * 8;   // ck
        lutT[(size_t)dst_row * 1024 + dst_col] = tile[tx][ty + i * 8];
    }
}

// ---------------- Kernel A2h: build pair tables in f16 ----------------
// Ph[p][j][m] = (f16)( lutT[2p*16 + (j&15)][m] + lutT[(2p+1)*16 + (j>>4)][m] )
__global__ __launch_bounds__(256) void k_build_h(const float* __restrict__ lutT,
                                                 _Float16* __restrict__ Ph) {
    int j = blockIdx.x;           // 0..255 code
    int p = blockIdx.y;           // 0..31 pair
    int klo = j & 15;
    int khi = j >> 4;
    int t = threadIdx.x;          // 0..255, 4 m each
    const float4* a = (const float4*)lutT + (size_t)(p * 32 + klo) * 256;
    const float4* b = (const float4*)lutT + (size_t)(p * 32 + 16 + khi) * 256;
    float4 va = a[t];
    float4 vb = b[t];
    half4v hv;
    hv.x = (_Float16)(va.x + vb.x);
    hv.y = (_Float16)(va.y + vb.y);
    hv.z = (_Float16)(va.z + vb.z);
    hv.w = (_Float16)(va.w + vb.w);
    ((half4v*)Ph)[(size_t)(p * 256 + j) * 256 + t] = hv;   // 8B store
}

// ---------------- Kernel B2: encode pair codes ----------------
__global__ __launch_bounds__(256) void k_encode2(const float* __restrict__ in,
                                                 const int* __restrict__ dims,
                                                 const float* __restrict__ th,
                                                 uint8_t* __restrict__ code) {
    __shared__ float rows[8][1028];   // +4 pad
    __shared__ float th_s[960];
    __shared__ int   dims_s[256];
    int t = threadIdx.x;
    dims_s[t] = dims[t];
    for (int i = t; i < 960; i += 256) th_s[i] = th[i];
    int n0 = blockIdx.x * 8;
    const float4* in4 = (const float4*)(in + (size_t)n0 * 1024);
#pragma unroll
    for (int i = 0; i < 8; ++i) {
        ((float4*)&rows[i][0])[t] = in4[i * 256 + t];
    }
    __syncthreads();
    int p = t >> 3;               // 0..31
    int r = t & 7;                // 0..7
    const float* trow = &rows[r][0];
    int cA = 2 * p, cB = 2 * p + 1;

    float xA[4], xB[4];
#pragma unroll
    for (int l = 0; l < 4; ++l) {
        xA[l] = trow[dims_s[cA * 4 + l]];
        xB[l] = trow[dims_s[cB * 4 + l]];
    }
    const float* tAp = &th_s[cA * 15];
    const float* tBp = &th_s[cB * 15];
    unsigned mA = 0, mB = 0;
#pragma unroll
    for (int i = 0; i < 15; ++i) {
        const int d = (i == 0) ? 0 : (i < 3) ? 1 : (i < 7) ? 2 : 3;  // compile-time
        mA |= ((unsigned)(xA[d] > tAp[i])) << i;
        mB |= ((unsigned)(xB[d] > tBp[i])) << i;
    }
    int nA = 0, nB = 0;
#pragma unroll
    for (int l = 0; l < 4; ++l) {
        nA = 2 * nA + 1 + ((mA >> nA) & 1);
        nB = 2 * nB + 1 + ((mB >> nB) & 1);
    }
    code[(size_t)p * N_ROWS + n0 + r] = (uint8_t)(((nB - 15) << 4) | (nA - 15));
}

// ---------------- Kernel C5: pipelined f16 accumulate ----------------
// Block 512 thr, tile 1024n x 32m. Slice per p: 256 rows x 64B f16 (16KB).
// 4-buffer ring (64KB -> 2 blocks/CU). Raw s_barrier + counted vmcnt:
// 2 stages + next code-load stay in flight across every barrier (T3/T4).
// Accumulate with v_fma_mix_f32 (f32 += f16*1.0), 1 VALU op per element.
__global__ __launch_bounds__(512, 4) void k_accum5(const float4* __restrict__ P4h,
                                                   const uint8_t* __restrict__ code,
                                                   float* __restrict__ out) {
    __shared__ float4 sl[4][1024];    // 4 x 16KB ring

    int t  = threadIdx.x;
    int mc = t & 3;                   // 16B chunk within row (4 chunks = 32 m)
    int ng = t >> 2;                  // 0..127, each owns 8 n rows
    int m0 = blockIdx.x * 32;
    int n0 = blockIdx.y * 1024;
    const int mch0 = m0 >> 3;         // float4 offset within P row (row = 128 float4)

    auto stage = [&](int buf, int p) {
#pragma unroll
        for (int it = 0; it < 2; ++it) {
            int idx = t + it * 512;                    // 0..1023 float4 within slice
            int row = idx >> 2;
            int ch  = idx & 3;
            const float4* src = P4h + ((size_t)(p * 256 + row)) * 128 + mch0 + ch;
            __builtin_amdgcn_global_load_lds((const __attribute__((address_space(1))) void*)src,
                                             (__attribute__((address_space(3))) void*)(&sl[buf][idx]),
                                             16, 0, 0);
        }
    };

    float acc[8][8];
#pragma unroll
    for (int j = 0; j < 8; ++j)
#pragma unroll
        for (int q = 0; q < 8; ++q) acc[j][q] = 0.f;

    const uint8_t* cp = code + n0 + ng * 8;

    // Prologue: code(0) first, then 3 stages in flight.
    uint64_t cd = *(const uint64_t*)cp;
    asm volatile("" ::: "memory");    // pin: cd load issues before stages
    stage(0, 0);
    stage(1, 1);
    stage(2, 2);

    // Per-iter vmem issue order (pinned): [nx code load][stage p+3].
    // Steady-state queue at wait point: stage(p)[2] stage(p+1)[2] nx(p)[1] stage(p+2)[2].
    // vmcnt(4) drains stage(p); compiler's auto-wait before cd-use covers nx;
    // stage(p+1..p+2) stay in flight across the barrier.
#define ACC_ITER(P_, WAIT_)                                                          \
    do {                                                                             \
        asm volatile("s_waitcnt vmcnt(" WAIT_ ")" ::: "memory");                     \
        asm volatile("s_barrier" ::: "memory");                                      \
        uint64_t nx = 0;                                                             \
        if ((P_) < 31) nx = *(const uint64_t*)(cp + (size_t)((P_) + 1) * N_ROWS);    \
        asm volatile("" ::: "memory"); /* pin: nx before stage issue */              \
        if ((P_) + 3 < 32) stage(((P_) + 3) & 3, (P_) + 3);                          \
        const float4* s = &sl[(P_) & 3][0];                                          \
        _Pragma("unroll")                                                            \
        for (int j = 0; j < 8; ++j) {                                                \
            int cv = (int)((cd >> (8 * j)) & 0xff);                                  \
            float4 v = s[cv * 4 + mc];                                               \
            asm("v_fma_mix_f32 %0, %8, 1.0, %0 op_sel_hi:[1,0,0]\n\t"                \
                "v_fma_mix_f32 %1, %8, 1.0, %1 op_sel:[1,0,0] op_sel_hi:[1,0,0]\n\t" \
                "v_fma_mix_f32 %2, %9, 1.0, %2 op_sel_hi:[1,0,0]\n\t"                \
                "v_fma_mix_f32 %3, %9, 1.0, %3 op_sel:[1,0,0] op_sel_hi:[1,0,0]\n\t" \
                "v_fma_mix_f32 %4, %10, 1.0, %4 op_sel_hi:[1,0,0]\n\t"               \
                "v_fma_mix_f32 %5, %10, 1.0, %5 op_sel:[1,0,0] op_sel_hi:[1,0,0]\n\t"\
                "v_fma_mix_f32 %6, %11, 1.0, %6 op_sel_hi:[1,0,0]\n\t"               \
                "v_fma_mix_f32 %7, %11, 1.0, %7 op_sel:[1,0,0] op_sel_hi:[1,0,0]"    \
                : "+v"(acc[j][0]), "+v"(acc[j][1]), "+v"(acc[j][2]), "+v"(acc[j][3]),\
                  "+v"(acc[j][4]), "+v"(acc[j][5]), "+v"(acc[j][6]), "+v"(acc[j][7]) \
                : "v"(v.x), "v"(v.y), "v"(v.z), "v"(v.w));                           \
        }                                                                            \
        cd = nx;                                                                     \
    } while (0)

    for (int p = 0; p < 30; ++p) ACC_ITER(p, "4");
    ACC_ITER(30, "3");
    ACC_ITER(31, "1");
#undef ACC_ITER

    float4* out4 = (float4*)out;
#pragma unroll
    for (int j = 0; j < 8; ++j) {
        int n = n0 + ng * 8 + j;
        size_t base = (size_t)n * 256 + (m0 >> 2) + mc * 2;
        out4[base]     = make_float4(acc[j][0], acc[j][1], acc[j][2], acc[j][3]);
        out4[base + 1] = make_float4(acc[j][4], acc[j][5], acc[j][6], acc[j][7]);
    }
}

// ================= Fallback path (ws too small): round-1 kernels =================
__global__ __launch_bounds__(256) void k_encode(const float* __restrict__ in,
                                                const int* __restrict__ dims,
                                                const float* __restrict__ th,
                                                uint8_t* __restrict__ leaf) {
    __shared__ float rows[8][1028];
    __shared__ float th_s[960];
    __shared__ int   dims_s[256];
    int t = threadIdx.x;
    dims_s[t] = dims[t];
    for (int i = t; i < 960; i += 256) th_s[i] = th[i];
    int n0 = blockIdx.x * 8;
    const float4* in4 = (const float4*)(in + (size_t)n0 * 1024);
#pragma unroll
    for (int i = 0; i < 8; ++i) {
        ((float4*)&rows[i][0])[t] = in4[i * 256 + t];
    }
    __syncthreads();
#pragma unroll
    for (int i = 0; i < 2; ++i) {
        int id = i * 256 + t;
        int c = id >> 3;
        int r = id & 7;
        int node = 0;
        const float* trow = &rows[r][0];
#pragma unroll
        for (int lvl = 0; lvl < 4; ++lvl) {
            float x   = trow[dims_s[c * 4 + lvl]];
            float thv = th_s[c * 15 + node];
            node = 2 * node + 1 + ((x > thv) ? 1 : 0);
        }
        leaf[(size_t)c * N_ROWS + n0 + r] = (uint8_t)(node - 15);
    }
}

__global__ __launch_bounds__(512) void k_accum(const float* __restrict__ lutT,
                                               const uint8_t* __restrict__ leaf,
                                               float* __restrict__ out) {
    __shared__ float4 sl[2][16][32];
    int t     = threadIdx.x;
    int mlane = t & 31;
    int ngrp  = t >> 5;
    int wave  = t >> 6;
    int lane  = t & 63;
    int srow  = 2 * wave + (lane >> 5);
    int schunk = lane & 31;
    int m0 = blockIdx.x * 128;
    int n0 = blockIdx.y * 128;
    const float4* lutT4 = (const float4*)lutT;
    auto stage = [&](int buf, int c) {
        const float4* src = lutT4 + ((size_t)(c * 16 + srow) * 256) + (m0 >> 2) + schunk;
        __builtin_amdgcn_global_load_lds((const __attribute__((address_space(1))) void*)src,
                                         (__attribute__((address_space(3))) void*)&sl[buf][2 * wave][0],
                                         16, 0, 0);
    };
    float4 acc[8];
#pragma unroll
    for (int j = 0; j < 8; ++j) acc[j] = make_float4(0.f, 0.f, 0.f, 0.f);
    const uint8_t* lp = leaf + n0 + ngrp * 8;
    uint64_t lv = *(const uint64_t*)lp;
    stage(0, 0);
#pragma unroll 2
    for (int c = 0; c < 64; ++c) {
        __syncthreads();
        if (c < 63) stage((c + 1) & 1, c + 1);
        uint64_t lv_next = (c < 63) ? *(const uint64_t*)(lp + (size_t)(c + 1) * N_ROWS) : 0ull;
        int buf = c & 1;
#pragma unroll
        for (int j = 0; j < 8; ++j) {
            int k = (int)((lv >> (8 * j)) & 15);
            float4 v = sl[buf][k][mlane];
            acc[j].x += v.x; acc[j].y += v.y; acc[j].z += v.z; acc[j].w += v.w;
        }
        lv = lv_next;
    }
    float4* out4 = (float4*)out;
#pragma unroll
    for (int j = 0; j < 8; ++j) {
        int n = n0 + ngrp * 8 + j;
        out4[(size_t)n * 256 + (m0 >> 2) + mlane] = acc[j];
    }
}

extern "C" void kernel_launch(void* const* d_in, const int* in_sizes, int n_in,
                              void* d_out, int out_size, void* d_ws, size_t ws_size,
                              hipStream_t stream) {
    const float* inputMatrix = (const float*)d_in[0];
    const int*   dims        = (const int*)d_in[1];
    const float* thresholds  = (const float*)d_in[2];
    const float* lut         = (const float*)d_in[3];
    float* out = (float*)d_out;

    float* lutT = (float*)d_ws;                                    // 4 MB

    const size_t NEED = (size_t)4 * 1024 * 1024   // lutT
                      + (size_t)16 * 1024 * 1024  // Ph (f16)
                      + (size_t)1 * 1024 * 1024;  // code

    if (ws_size >= NEED) {
        _Float16* Ph   = (_Float16*)((char*)d_ws + (size_t)4 * 1024 * 1024); // 16 MB
        uint8_t* codep = (uint8_t*)d_ws + (size_t)20 * 1024 * 1024;          // 1 MB

        k_transpose<<<dim3(32, 32), dim3(32, 8), 0, stream>>>(lut, lutT);
        k_build_h<<<dim3(256, 32), 256, 0, stream>>>(lutT, Ph);
        k_encode2<<<N_ROWS / 8, 256, 0, stream>>>(inputMatrix, dims, thresholds, codep);
        k_accum5<<<dim3(M_OUT / 32, N_ROWS / 1024), 512, 0, stream>>>((const float4*)Ph, codep, out);
    } else {
        uint8_t* leaf = (uint8_t*)d_ws + (size_t)4 * 1024 * 1024;
        k_transpose<<<dim3(32, 32), dim3(32, 8), 0, stream>>>(lut, lutT);
        k_encode<<<N_ROWS / 8, 256, 0, stream>>>(inputMatrix, dims, thresholds, leaf);
        k_accum<<<dim3(M_OUT / 128, N_ROWS / 128), 512, 0, stream>>>(lutT, leaf, out);
    }
}

// Round 7
// 310.778 us; speedup vs baseline: 1.2171x; 1.0250x over previous
//
#include <hip/hip_runtime.h>
#include <stdint.h>

#define N_ROWS 32768
#define D_DIM  1024
#define C_TREES 64
#define K_LEAF 16
#define M_OUT  1024

typedef _Float16 half8v __attribute__((ext_vector_type(8)));
typedef _Float16 half4v __attribute__((ext_vector_type(4)));

// 8 x (f32 += f16) in 8 VOP3P ops: v_fma_mix_f32 acc, h, 1.0, acc
__device__ __forceinline__ void fma8(float* a, float4 v) {
    asm("v_fma_mix_f32 %0, %8, 1.0, %0 op_sel_hi:[1,0,0]\n\t"
        "v_fma_mix_f32 %1, %8, 1.0, %1 op_sel:[1,0,0] op_sel_hi:[1,0,0]\n\t"
        "v_fma_mix_f32 %2, %9, 1.0, %2 op_sel_hi:[1,0,0]\n\t"
        "v_fma_mix_f32 %3, %9, 1.0, %3 op_sel:[1,0,0] op_sel_hi:[1,0,0]\n\t"
        "v_fma_mix_f32 %4, %10, 1.0, %4 op_sel_hi:[1,0,0]\n\t"
        "v_fma_mix_f32 %5, %10, 1.0, %5 op_sel:[1,0,0] op_sel_hi:[1,0,0]\n\t"
        "v_fma_mix_f32 %6, %11, 1.0, %6 op_sel_hi:[1,0,0]\n\t"
        "v_fma_mix_f32 %7, %11, 1.0, %7 op_sel:[1,0,0] op_sel_hi:[1,0,0]"
        : "+v"(a[0]), "+v"(a[1]), "+v"(a[2]), "+v"(a[3]),
          "+v"(a[4]), "+v"(a[5]), "+v"(a[6]), "+v"(a[7])
        : "v"(v.x), "v"(v.y), "v"(v.z), "v"(v.w));
}

// ---------------- Kernel A: transpose lut (M, C*K=1024) -> lutT (C*K, M) ----------------
__global__ __launch_bounds__(256) void k_transpose(const float* __restrict__ lut,
                                                   float* __restrict__ lutT) {
    __shared__ float tile[32][33];
    int bx = blockIdx.x;
    int by = blockIdx.y;
    int tx = threadIdx.x;
    int ty = threadIdx.y;
    int src_col = bx * 32 + tx;
#pragma unroll
    for (int i = 0; i < 4; ++i) {
        int src_row = by * 32 + ty + i * 8;
        tile[ty + i * 8][tx] = lut[(size_t)src_row * 1024 + src_col];
    }
    __syncthreads();
    int dst_col = by * 32 + tx;
#pragma unroll
    for (int i = 0; i < 4; ++i) {
        int dst_row = bx * 32 + ty + i * 8;
        lutT[(size_t)dst_row * 1024 + dst_col] = tile[tx][ty + i * 8];
    }
}

// ---------------- Kernel A2t: build pair tables, f16, m-tile-contiguous ----------------
// Pt[tile][p*256+j][32 m] (halves): tile = m/32. Slice (tile,p) = contiguous 16KB.
__global__ __launch_bounds__(256) void k_build_ht(const float* __restrict__ lutT,
                                                  _Float16* __restrict__ Pt) {
    int j = blockIdx.x;           // 0..255 code
    int p = blockIdx.y;           // 0..31 pair
    int klo = j & 15;
    int khi = j >> 4;
    int t = threadIdx.x;          // 0..255, 4 m each
    const float4* a = (const float4*)lutT + (size_t)(p * 32 + klo) * 256;
    const float4* b = (const float4*)lutT + (size_t)(p * 32 + 16 + khi) * 256;
    float4 va = a[t];
    float4 vb = b[t];
    half4v hv;
    hv.x = (_Float16)(va.x + vb.x);
    hv.y = (_Float16)(va.y + vb.y);
    hv.z = (_Float16)(va.z + vb.z);
    hv.w = (_Float16)(va.w + vb.w);
    int tile = t >> 3;            // m-tile (m = 4t)
    // half4 units: tile stride 65536, row (p*256+j) stride 8, within-row (t&7)
    ((half4v*)Pt)[(size_t)tile * 65536 + (size_t)(p * 256 + j) * 8 + (t & 7)] = hv;
}

// ---------------- Kernel B2: encode pair codes ----------------
__global__ __launch_bounds__(256) void k_encode2(const float* __restrict__ in,
                                                 const int* __restrict__ dims,
                                                 const float* __restrict__ th,
                                                 uint8_t* __restrict__ code) {
    __shared__ float rows[8][1028];   // +4 pad
    __shared__ float th_s[960];
    __shared__ int   dims_s[256];
    int t = threadIdx.x;
    dims_s[t] = dims[t];
    for (int i = t; i < 960; i += 256) th_s[i] = th[i];
    int n0 = blockIdx.x * 8;
    const float4* in4 = (const float4*)(in + (size_t)n0 * 1024);
#pragma unroll
    for (int i = 0; i < 8; ++i) {
        ((float4*)&rows[i][0])[t] = in4[i * 256 + t];
    }
    __syncthreads();
    int p = t >> 3;
    int r = t & 7;
    const float* trow = &rows[r][0];
    int cA = 2 * p, cB = 2 * p + 1;

    float xA[4], xB[4];
#pragma unroll
    for (int l = 0; l < 4; ++l) {
        xA[l] = trow[dims_s[cA * 4 + l]];
        xB[l] = trow[dims_s[cB * 4 + l]];
    }
    const float* tAp = &th_s[cA * 15];
    const float* tBp = &th_s[cB * 15];
    unsigned mA = 0, mB = 0;
#pragma unroll
    for (int i = 0; i < 15; ++i) {
        const int d = (i == 0) ? 0 : (i < 3) ? 1 : (i < 7) ? 2 : 3;
        mA |= ((unsigned)(xA[d] > tAp[i])) << i;
        mB |= ((unsigned)(xB[d] > tBp[i])) << i;
    }
    int nA = 0, nB = 0;
#pragma unroll
    for (int l = 0; l < 4; ++l) {
        nA = 2 * nA + 1 + ((mA >> nA) & 1);
        nB = 2 * nB + 1 + ((mB >> nB) & 1);
    }
    code[(size_t)p * N_ROWS + n0 + r] = (uint8_t)(((nB - 15) << 4) | (nA - 15));
}

// ---------------- Kernel C6: split-pipe accumulate ----------------
// out[n,m] = sum_p Pt[tile][p*256+code(p,n)][m...]. 16 iters, each covers p=2i (LDS)
// and p=2i+1 (direct L2/L1 gather). Even slices staged via 3x16KB ring
// (48KB LDS -> target 3 blocks/CU), uniform vmcnt(4) top-wait keeps next stage
// + code prefetch in flight across every barrier. Gather waits compiler-managed.
__global__ __launch_bounds__(512, 6) void k_accum6(const _Float16* __restrict__ Pt,
                                                   const uint8_t* __restrict__ code,
                                                   float* __restrict__ out) {
    __shared__ float4 sl[3][1024];    // 3 x 16KB ring

    int t  = threadIdx.x;
    int mc = t & 3;                   // 16B chunk within 32-m row
    int ng = t >> 2;                  // 0..127, each owns 4 n rows
    int tile = blockIdx.x;            // m0 = tile*32
    int n0 = blockIdx.y * 512;
    const float4* Pt4 = (const float4*)Pt + (size_t)tile * 32768;  // tile base (float4)

    auto stage = [&](int buf, int slice) {
#pragma unroll
        for (int it = 0; it < 2; ++it) {
            int idx = t + it * 512;                    // 0..1023 float4 within slice
            const float4* src = Pt4 + slice * 1024 + idx;   // contiguous 16KB
            __builtin_amdgcn_global_load_lds((const __attribute__((address_space(1))) void*)src,
                                             (__attribute__((address_space(3))) void*)(&sl[buf][idx]),
                                             16, 0, 0);
        }
    };

    float acc[4][8];
#pragma unroll
    for (int j = 0; j < 4; ++j)
#pragma unroll
        for (int q = 0; q < 8; ++q) acc[j][q] = 0.f;

    const uint8_t* cp = code + n0 + ng * 4;
    uint32_t cdE = *(const uint32_t*)cp;                       // p=0
    uint32_t cdO = *(const uint32_t*)(cp + N_ROWS);            // p=1
    asm volatile("" ::: "memory");    // pin: code loads before stages
    stage(0, 0);                      // slice p=0
    stage(1, 2);                      // slice p=2
    int bc = 0;                       // ring buf holding this iter's even slice

    for (int i = 0; i < 16; ++i) {
        // Drain the stage issued 2 iters ago (own-wave portion), keep newer
        // stage(2) + codes(2) in flight; barrier makes it block-wide.
        asm volatile("s_waitcnt vmcnt(4)" ::: "memory");
        asm volatile("s_barrier" ::: "memory");

        // Odd-slice gathers (L1/L2): o = 2i+1, 16KB slice, data-dep on cdO.
        int o = 2 * i + 1;
        float4 gv0, gv1, gv2, gv3;
        {
            int c0 = (int)(cdO & 0xff);
            int c1 = (int)((cdO >> 8) & 0xff);
            int c2 = (int)((cdO >> 16) & 0xff);
            int c3 = (int)((cdO >> 24) & 0xff);
            int ob = o << 8;
            gv0 = Pt4[(ob + c0) * 4 + mc];
            gv1 = Pt4[(ob + c1) * 4 + mc];
            gv2 = Pt4[(ob + c2) * 4 + mc];
            gv3 = Pt4[(ob + c3) * 4 + mc];
        }
        // Next iteration's codes (clamped dummy at the end).
        int ip = (i < 15) ? (i + 1) : 0;
        uint32_t cdE2 = *(const uint32_t*)(cp + (size_t)(2 * ip) * N_ROWS);
        uint32_t cdO2 = *(const uint32_t*)(cp + (size_t)(2 * ip + 1) * N_ROWS);
        asm volatile("" ::: "memory");    // pin: gathers+codes issue before stage
        // Stage even slice for iter i+2 (dummy re-stage of slice 0 at the tail).
        int ns = (i < 14) ? (2 * i + 4) : 0;
        int bs = bc + 2; if (bs >= 3) bs -= 3;
        stage(bs, ns);

        // Even slice from LDS.
        const float4* s = &sl[bc][0];
#pragma unroll
        for (int j = 0; j < 4; ++j) {
            int cv = (int)((cdE >> (8 * j)) & 0xff);
            float4 v = s[cv * 4 + mc];
            fma8(acc[j], v);
        }
        // Odd slice from gathered registers (p ascending order preserved per j).
        fma8(acc[0], gv0);
        fma8(acc[1], gv1);
        fma8(acc[2], gv2);
        fma8(acc[3], gv3);

        cdE = cdE2; cdO = cdO2;
        bc = (bc == 2) ? 0 : bc + 1;
    }

    float4* out4 = (float4*)out;
#pragma unroll
    for (int j = 0; j < 4; ++j) {
        int n = n0 + ng * 4 + j;
        size_t base = (size_t)n * 256 + tile * 8 + mc * 2;
        out4[base]     = make_float4(acc[j][0], acc[j][1], acc[j][2], acc[j][3]);
        out4[base + 1] = make_float4(acc[j][4], acc[j][5], acc[j][6], acc[j][7]);
    }
}

// ================= Fallback path (ws too small): round-1 kernels =================
__global__ __launch_bounds__(256) void k_encode(const float* __restrict__ in,
                                                const int* __restrict__ dims,
                                                const float* __restrict__ th,
                                                uint8_t* __restrict__ leaf) {
    __shared__ float rows[8][1028];
    __shared__ float th_s[960];
    __shared__ int   dims_s[256];
    int t = threadIdx.x;
    dims_s[t] = dims[t];
    for (int i = t; i < 960; i += 256) th_s[i] = th[i];
    int n0 = blockIdx.x * 8;
    const float4* in4 = (const float4*)(in + (size_t)n0 * 1024);
#pragma unroll
    for (int i = 0; i < 8; ++i) {
        ((float4*)&rows[i][0])[t] = in4[i * 256 + t];
    }
    __syncthreads();
#pragma unroll
    for (int i = 0; i < 2; ++i) {
        int id = i * 256 + t;
        int c = id >> 3;
        int r = id & 7;
        int node = 0;
        const float* trow = &rows[r][0];
#pragma unroll
        for (int lvl = 0; lvl < 4; ++lvl) {
            float x   = trow[dims_s[c * 4 + lvl]];
            float thv = th_s[c * 15 + node];
            node = 2 * node + 1 + ((x > thv) ? 1 : 0);
        }
        leaf[(size_t)c * N_ROWS + n0 + r] = (uint8_t)(node - 15);
    }
}

__global__ __launch_bounds__(512) void k_accum(const float* __restrict__ lutT,
                                               const uint8_t* __restrict__ leaf,
                                               float* __restrict__ out) {
    __shared__ float4 sl[2][16][32];
    int t     = threadIdx.x;
    int mlane = t & 31;
    int ngrp  = t >> 5;
    int wave  = t >> 6;
    int lane  = t & 63;
    int srow  = 2 * wave + (lane >> 5);
    int schunk = lane & 31;
    int m0 = blockIdx.x * 128;
    int n0 = blockIdx.y * 128;
    const float4* lutT4 = (const float4*)lutT;
    auto stage = [&](int buf, int c) {
        const float4* src = lutT4 + ((size_t)(c * 16 + srow) * 256) + (m0 >> 2) + schunk;
        __builtin_amdgcn_global_load_lds((const __attribute__((address_space(1))) void*)src,
                                         (__attribute__((address_space(3))) void*)&sl[buf][2 * wave][0],
                                         16, 0, 0);
    };
    float4 acc[8];
#pragma unroll
    for (int j = 0; j < 8; ++j) acc[j] = make_float4(0.f, 0.f, 0.f, 0.f);
    const uint8_t* lp = leaf + n0 + ngrp * 8;
    uint64_t lv = *(const uint64_t*)lp;
    stage(0, 0);
#pragma unroll 2
    for (int c = 0; c < 64; ++c) {
        __syncthreads();
        if (c < 63) stage((c + 1) & 1, c + 1);
        uint64_t lv_next = (c < 63) ? *(const uint64_t*)(lp + (size_t)(c + 1) * N_ROWS) : 0ull;
        int buf = c & 1;
#pragma unroll
        for (int j = 0; j < 8; ++j) {
            int k = (int)((lv >> (8 * j)) & 15);
            float4 v = sl[buf][k][mlane];
            acc[j].x += v.x; acc[j].y += v.y; acc[j].z += v.z; acc[j].w += v.w;
        }
        lv = lv_next;
    }
    float4* out4 = (float4*)out;
#pragma unroll
    for (int j = 0; j < 8; ++j) {
        int n = n0 + ngrp * 8 + j;
        out4[(size_t)n * 256 + (m0 >> 2) + mlane] = acc[j];
    }
}

extern "C" void kernel_launch(void* const* d_in, const int* in_sizes, int n_in,
                              void* d_out, int out_size, void* d_ws, size_t ws_size,
                              hipStream_t stream) {
    const float* inputMatrix = (const float*)d_in[0];
    const int*   dims        = (const int*)d_in[1];
    const float* thresholds  = (const float*)d_in[2];
    const float* lut         = (const float*)d_in[3];
    float* out = (float*)d_out;

    float* lutT = (float*)d_ws;                                    // 4 MB

    const size_t NEED = (size_t)4 * 1024 * 1024   // lutT
                      + (size_t)16 * 1024 * 1024  // Pt (f16, tiled)
                      + (size_t)1 * 1024 * 1024;  // code

    if (ws_size >= NEED) {
        _Float16* Pt   = (_Float16*)((char*)d_ws + (size_t)4 * 1024 * 1024); // 16 MB
        uint8_t* codep = (uint8_t*)d_ws + (size_t)20 * 1024 * 1024;          // 1 MB

        k_transpose<<<dim3(32, 32), dim3(32, 8), 0, stream>>>(lut, lutT);
        k_build_ht<<<dim3(256, 32), 256, 0, stream>>>(lutT, Pt);
        k_encode2<<<N_ROWS / 8, 256, 0, stream>>>(inputMatrix, dims, thresholds, codep);
        k_accum6<<<dim3(M_OUT / 32, N_ROWS / 512), 512, 0, stream>>>(Pt, codep, out);
    } else {
        uint8_t* leaf = (uint8_t*)d_ws + (size_t)4 * 1024 * 1024;
        k_transpose<<<dim3(32, 32), dim3(32, 8), 0, stream>>>(lut, lutT);
        k_encode<<<N_ROWS / 8, 256, 0, stream>>>(inputMatrix, dims, thresholds, leaf);
        k_accum<<<dim3(M_OUT / 128, N_ROWS / 128), 512, 0, stream>>>(lutT, leaf, out);
    }
}